// Round 2
// baseline (645.774 us; speedup 1.0000x reference)
//
#include <hip/hip_runtime.h>
#include <cstdint>

#define BATCH 8
#define NPTS  4096
#define MPTS  1024
#define DIM   64

typedef float v2f __attribute__((ext_vector_type(2)));
typedef unsigned long long u64;
typedef unsigned int u32;

// Pack (f32 distance bits, aux) into a double whose VALUE ordering equals the
// u64 bit-pattern ordering: hi word = f32 bits of a non-negative float
// (<= FLT_MAX bits 0x7F7FFFFF -> f64 exponent <= 2039, sign 0 -> positive
// finite double). So v_max_f64 / v_min_f64 (1 inst each) give exact u64
// max/min — replacing the 3-inst v_cmp_u64+2*cndmask sequence.
__device__ __forceinline__ double mk_key(float m, u32 aux) {
  const u64 k = ((u64)__float_as_uint(m) << 32) | (u64)aux;
  return __longlong_as_double((long long)k);
}
__device__ __forceinline__ u32 key_lo(double d) {
  return (u32)(u64)__double_as_longlong(d);
}

// One DPP step of a 64-lane f64-key max reduction. bound_ctrl=true -> invalid
// source lanes read 0.0, the identity for max of positive keys.
#define WAVE_MAX_F64_STEP(x, ctrl)                                                    \
  {                                                                                   \
    const u64 xu_ = (u64)__double_as_longlong(x);                                     \
    const int lo_ = __builtin_amdgcn_update_dpp(0, (int)(u32)xu_, (ctrl), 0xf, 0xf, true);  \
    const int hi_ = __builtin_amdgcn_update_dpp(0, (int)(u32)(xu_ >> 32), (ctrl), 0xf, 0xf, true); \
    const double y_ = __longlong_as_double((long long)(((u64)(u32)hi_ << 32) | (u64)(u32)lo_)); \
    (x) = fmax((x), y_);                                                              \
  }

// -------------------- Kernel 1: farthest point sampling --------------------
// One block per cloud. R2 change: 512 threads (8 waves -> 2 waves/SIMD).
// Rationale: rocprof shows ~61% VALU-busy on active CUs with 1 wave/SIMD;
// the ~40% stall (f64-max dep chains, DPP chain, LDS round-trip after the
// barrier) has nothing to hide it. Two co-resident waves per SIMD interleave
// issue during each other's stalls. Per-thread work halves (8 points = 4
// pk-groups); reduction widens to 8 wave slots (combine tree of 7 v_max_f64).
// Still: 1 barrier/iter, zero VMEM in the steady-state loop (R1), register
// history of winners written with 2 coalesced stores/thread at the end.
__global__ __launch_bounds__(512) void fps_kernel(const float* __restrict__ pos,
                                                  int* __restrict__ gidx) {
#pragma clang fp contract(off)
  const int b = blockIdx.x;
  const int t = threadIdx.x;
  const float* p = pos + (size_t)b * NPTS * 3;

  __shared__ float4 sp[NPTS];
  __shared__ double red[2][8];

  v2f px[4], py[4], pz[4], mind[4];
#pragma unroll
  for (int k = 0; k < 8; ++k) {
    const int i = t + k * 512;
    const float a = p[3 * i + 0];
    const float c = p[3 * i + 1];
    const float d = p[3 * i + 2];
    sp[i] = make_float4(a, c, d, 0.0f);
    px[k >> 1][k & 1] = a;
    py[k >> 1][k & 1] = c;
    pz[k >> 1][k & 1] = d;
    mind[k >> 1][k & 1] = 3.402823466e+38f;  // finfo(float32).max
  }
  __syncthreads();

  float4 w = sp[0];
  float lx = w.x, ly = w.y, lz = w.z;

  // Register history of winner indices: thread t owns iterations t, t+512.
  // h0 stays 0 for t==0 (the deterministic start at local idx 0).
  int h0 = 0, h1 = 0;
  const int it1 = t + 512;

  for (int it = 1; it < MPTS; ++it) {
    const v2f vlx = {lx, lx}, vly = {ly, ly}, vlz = {lz, lz};
    double pg[4];
#pragma unroll
    for (int g = 0; g < 4; ++g) {
      // strict fp32, no contraction: ((dx*dx + dy*dy) + dz*dz), per element
      const v2f dx = px[g] - vlx;
      const v2f dy = py[g] - vly;
      const v2f dz = pz[g] - vlz;
      const v2f d = (dx * dx + dy * dy) + dz * dz;
      const v2f m = __builtin_elementwise_min(mind[g], d);
      mind[g] = m;
      const double p0 = mk_key(m[0], ~(u32)(t + (2 * g) * 512));      // hoisted consts
      const double p1 = mk_key(m[1], ~(u32)(t + (2 * g + 1) * 512));  // tie -> larger ~idx
      pg[g] = fmax(p0, p1);
    }
    // thread-local tree (all single v_max_f64)
    double best = fmax(fmax(pg[0], pg[1]), fmax(pg[2], pg[3]));

    // 64-lane wave max via DPP: rows (16) then cross-row bcasts; lane 63 final.
    WAVE_MAX_F64_STEP(best, 0x111);  // row_shr:1
    WAVE_MAX_F64_STEP(best, 0x112);  // row_shr:2
    WAVE_MAX_F64_STEP(best, 0x114);  // row_shr:4
    WAVE_MAX_F64_STEP(best, 0x118);  // row_shr:8
    WAVE_MAX_F64_STEP(best, 0x142);  // row_bcast:15
    WAVE_MAX_F64_STEP(best, 0x143);  // row_bcast:31

    const int buf = it & 1;  // double-buffered slots: 1 barrier/iter
    if ((t & 63) == 63) red[buf][t >> 6] = best;
    __syncthreads();

    const double c01 = fmax(red[buf][0], red[buf][1]);
    const double c23 = fmax(red[buf][2], red[buf][3]);
    const double c45 = fmax(red[buf][4], red[buf][5]);
    const double c67 = fmax(red[buf][6], red[buf][7]);
    const double c = fmax(fmax(c01, c23), fmax(c45, c67));
    const u32 widx = ~key_lo(c);  // low word = ~idx

    w = sp[widx];  // broadcast read (same address all lanes)
    lx = w.x; ly = w.y; lz = w.z;

    // off-critical-path register history update (2x cmp+cndmask, no VMEM)
    h0 = (it == t)   ? (int)widx : h0;
    h1 = (it == it1) ? (int)widx : h1;
  }

  // Epilogue: 2 coalesced stores per thread write all M winner indices.
  const int base = b * MPTS;
  const int goff = b * NPTS;
  gidx[base + t]       = goff + h0;
  gidx[base + 512 + t] = goff + h1;
}

// -------------------- Kernel 2: k=1 nearest neighbor -----------------------
// B*32 blocks x 256 threads; 128 hr points per block, 2 threads per point
// splitting the M=1024 lr points in half; packed fp32 over lr pairs.
// Argmin key: (dist_bits<<32)|j -> min = smallest dist, tie -> smallest j
// (matches np.argmin); 64-bit mins via single v_min_f64. Pair combine via
// one shfl_xor(1).
__global__ __launch_bounds__(256) void nn_kernel(const float* __restrict__ pos,
                                                 const int* __restrict__ gidx,
                                                 int* __restrict__ nng) {
#pragma clang fp contract(off)
  const int b = blockIdx.x >> 5;
  const int chunk = blockIdx.x & 31;
  const int t = threadIdx.x;

  __shared__ float lrx[MPTS], lry[MPTS], lrz[MPTS];
  for (int j = t; j < MPTS; j += 256) {
    const int g = gidx[b * MPTS + j];
    lrx[j] = pos[3 * g + 0];
    lry[j] = pos[3 * g + 1];
    lrz[j] = pos[3 * g + 2];
  }
  __syncthreads();

  const int pt = chunk * 128 + (t >> 1);
  const int half = t & 1;
  const int i = b * NPTS + pt;  // global hr point index
  const float x = pos[3 * i + 0];
  const float y = pos[3 * i + 1];
  const float z = pos[3 * i + 2];
  const v2f vx = {x, x}, vy = {y, y}, vz = {z, z};

  double best = __longlong_as_double(0x7FEFFFFFFFFFFFFFll);  // +DBL_MAX > all keys
  const int j0 = half * 512;
#pragma unroll 4
  for (int s = 0; s < 256; ++s) {
    const int j = j0 + 2 * s;
    const v2f qx = *(const v2f*)&lrx[j];
    const v2f qy = *(const v2f*)&lry[j];
    const v2f qz = *(const v2f*)&lrz[j];
    const v2f dx = vx - qx;
    const v2f dy = vy - qy;
    const v2f dz = vz - qz;
    const v2f d = (dx * dx + dy * dy) + dz * dz;
    const double p0 = mk_key(d[0], (u32)j);
    const double p1 = mk_key(d[1], (u32)(j + 1));
    best = fmin(best, fmin(p0, p1));
  }
  // pair combine across the two halves (lanes differ only in bit 0)
  const u64 bu = (u64)__double_as_longlong(best);
  const u64 ou = ((u64)(u32)__shfl_xor((int)(bu >> 32), 1, 64) << 32) |
                 (u64)(u32)__shfl_xor((int)(u32)bu, 1, 64);
  best = fmin(best, __longlong_as_double((long long)ou));
  if (half == 0) nng[i] = gidx[b * MPTS + (int)key_lo(best)];
}

// -------------------- Kernel 3: output assembly ----------------------------
// One wave per output row. Row = [x(64) | pos(3) | x[g](64) | pos[g](3)].
// Also writes output 1 (zeros, [B*N,3]) and output 2 (batch ids as floats).
__global__ __launch_bounds__(256) void assemble_kernel(const float* __restrict__ x,
                                                       const float* __restrict__ pos,
                                                       const int* __restrict__ batch,
                                                       const int* __restrict__ nng,
                                                       float* __restrict__ out) {
  const int w = (int)((blockIdx.x * 256 + threadIdx.x) >> 6);  // row
  const int lane = threadIdx.x & 63;
  if (w >= BATCH * NPTS) return;
  const int g = nng[w];

  float* o = out + (size_t)w * 134;
  o[lane] = x[(size_t)w * DIM + lane];
  o[67 + lane] = x[(size_t)g * DIM + lane];
  if (lane < 3) {
    o[64 + lane] = pos[3 * w + lane];
    o[131 + lane] = pos[3 * g + lane];
  }

  float* o2 = out + (size_t)BATCH * NPTS * 134;  // zeros output [B*N,3]
  if (lane < 3) o2[3 * w + lane] = 0.0f;
  float* o3 = o2 + (size_t)BATCH * NPTS * 3;     // batch output [B*N]
  if (lane == 0) o3[w] = (float)batch[w];
}

// ---------------------------------------------------------------------------
extern "C" void kernel_launch(void* const* d_in, const int* in_sizes, int n_in,
                              void* d_out, int out_size, void* d_ws, size_t ws_size,
                              hipStream_t stream) {
  const float* x = (const float*)d_in[0];
  const float* pos = (const float*)d_in[1];
  const int* batch = (const int*)d_in[2];

  int* gidx = (int*)d_ws;            // [B*M] global indices of sampled points
  int* nng = gidx + BATCH * MPTS;    // [B*N] global index of nearest lr point

  float* out = (float*)d_out;

  fps_kernel<<<BATCH, 512, 0, stream>>>(pos, gidx);
  nn_kernel<<<BATCH * 32, 256, 0, stream>>>(pos, gidx, nng);
  assemble_kernel<<<(BATCH * NPTS * 64) / 256, 256, 0, stream>>>(x, pos, batch, nng, out);
}

// Round 3
// 604.213 us; speedup vs baseline: 1.0688x; 1.0688x over previous
//
#include <hip/hip_runtime.h>
#include <cstdint>

#define BATCH 8
#define NPTS  4096
#define MPTS  1024
#define DIM   64

typedef float v2f __attribute__((ext_vector_type(2)));
typedef unsigned long long u64;
typedef unsigned int u32;

// Pack (f32 distance bits, aux) into a double whose VALUE ordering equals the
// u64 bit-pattern ordering: hi word = f32 bits of a non-negative float
// (<= FLT_MAX bits 0x7F7FFFFF -> f64 exponent <= 2039, sign 0 -> positive
// finite double). So v_max_f64 / v_min_f64 give exact u64 max/min.
__device__ __forceinline__ double mk_key(float m, u32 aux) {
  const u64 k = ((u64)__float_as_uint(m) << 32) | (u64)aux;
  return __longlong_as_double((long long)k);
}
__device__ __forceinline__ u32 key_lo(double d) {
  return (u32)(u64)__double_as_longlong(d);
}
__device__ __forceinline__ u32 umax_(u32 a, u32 b) { return a > b ? a : b; }

// One DPP step of a 64-lane f32 max prefix/reduce. bound_ctrl=true -> invalid
// source lanes read 0 (= +0.0f), identity for max of non-negative values.
#define WAVE_MAX_F32_STEP(x, ctrl)                                                    \
  {                                                                                   \
    const int y_ = __builtin_amdgcn_update_dpp(0, __float_as_int(x), (ctrl), 0xf, 0xf, true); \
    (x) = fmaxf((x), __int_as_float(y_));                                             \
  }

// One DPP step of a 64-lane u32 max reduce. 0 is the identity.
#define WAVE_MAX_U32_STEP(x, ctrl)                                                    \
  {                                                                                   \
    const int y_ = __builtin_amdgcn_update_dpp(0, (int)(x), (ctrl), 0xf, 0xf, true);  \
    (x) = umax_((x), (u32)y_);                                                        \
  }

// -------------------- Kernel 1: farthest point sampling --------------------
// One block per cloud, 256 threads (4 waves, 1 wave/SIMD — R2 showed the loop
// is VALU-issue-bound per SIMD; extra waves duplicate reduction overhead).
// R3 change: the argmax reduction no longer uses 64-bit fmax in the hot path
// (measured VALUBusy implies v_max_f64 ~16cy; 24 of them dominated the iter).
// New per-iteration reduction, exact argmax + tie -> smallest idx:
//   1. f32 value max tree over the thread's 16 mind values (15 v_max_f32),
//      keeping intermediates.
//   2. Equality-descent down the tree -> leftmost slot k* equal to the local
//      max (4 v_cmp_eq + ~11 cndmask). Exact ties: left-first.
//   3. Wave value max: 4 row_shr DPP f32 steps -> row maxes at lanes
//      15/31/47/63; v_readlane x4 -> SALU s_max_u32 tree (free pipe) ->
//      wave max wv in an SGPR, broadcast to all lanes for free.
//   4. cand = (my local max bits == wv) ? ~(t + k*<<8) : 0; 6-step DPP
//      v_max_u32 chain -> lane63 holds ~(smallest matching idx).
//   5. lane63 writes the SAME u64 key {val_bits:hi, ~idx:lo} as before; the
//      post-barrier combine (3 fmax_f64 only), extract, sp[widx] broadcast
//      read, and register winner-history are unchanged from R1.
// Steady-state loop still has zero VMEM (R1); gidx written in the epilogue.
__global__ __launch_bounds__(256) void fps_kernel(const float* __restrict__ pos,
                                                  int* __restrict__ gidx) {
#pragma clang fp contract(off)
  const int b = blockIdx.x;
  const int t = threadIdx.x;
  const float* p = pos + (size_t)b * NPTS * 3;

  __shared__ float4 sp[NPTS];
  __shared__ double red[2][4];

  v2f px[8], py[8], pz[8], mind[8];
#pragma unroll
  for (int k = 0; k < 16; ++k) {
    const int i = t + k * 256;
    const float a = p[3 * i + 0];
    const float c = p[3 * i + 1];
    const float d = p[3 * i + 2];
    sp[i] = make_float4(a, c, d, 0.0f);
    px[k >> 1][k & 1] = a;
    py[k >> 1][k & 1] = c;
    pz[k >> 1][k & 1] = d;
    mind[k >> 1][k & 1] = 3.402823466e+38f;  // finfo(float32).max
  }
  __syncthreads();

  float4 w = sp[0];
  float lx = w.x, ly = w.y, lz = w.z;

  // Register history of winner indices: thread t owns iterations
  // t, t+256, t+512, t+768. h0 stays 0 for t==0 (deterministic start).
  int h0 = 0, h1 = 0, h2 = 0, h3 = 0;
  const int it1 = t + 256, it2 = t + 512, it3 = t + 768;

  for (int it = 1; it < MPTS; ++it) {
    const v2f vlx = {lx, lx}, vly = {ly, ly}, vlz = {lz, lz};
#pragma unroll
    for (int g = 0; g < 8; ++g) {
      // strict fp32, no contraction: ((dx*dx + dy*dy) + dz*dz), per element
      const v2f dx = px[g] - vlx;
      const v2f dy = py[g] - vly;
      const v2f dz = pz[g] - vlz;
      const v2f d = (dx * dx + dy * dy) + dz * dz;
      mind[g] = __builtin_elementwise_min(mind[g], d);
    }

    // ---- local f32 value max tree (slot k = 2g+h, global idx t + 256k) ----
    const float v0 = mind[0][0], v1 = mind[0][1], v2 = mind[1][0], v3 = mind[1][1];
    const float v4 = mind[2][0], v5 = mind[2][1], v6 = mind[3][0], v7 = mind[3][1];
    const float v8 = mind[4][0], v9 = mind[4][1], v10 = mind[5][0], v11 = mind[5][1];
    const float v12 = mind[6][0], v13 = mind[6][1], v14 = mind[7][0], v15 = mind[7][1];
    const float a0 = fmaxf(v0, v1),  a1 = fmaxf(v2, v3);
    const float a2 = fmaxf(v4, v5),  a3 = fmaxf(v6, v7);
    const float a4 = fmaxf(v8, v9),  a5 = fmaxf(v10, v11);
    const float a6 = fmaxf(v12, v13), a7 = fmaxf(v14, v15);
    const float b0 = fmaxf(a0, a1), b1 = fmaxf(a2, a3);
    const float b2 = fmaxf(a4, a5), b3 = fmaxf(a6, a7);
    const float c0 = fmaxf(b0, b1), c1 = fmaxf(b2, b3);
    const float m16 = fmaxf(c0, c1);

    // ---- equality-descent: leftmost slot with value == m16 (exact ties) ----
    const bool e3 = (c0 == m16);           // true -> slots 0-7
    const float bL = e3 ? b0 : b2;         // left child of chosen half
    const bool e2 = (bL == m16);           // true -> first quarter of half
    const float aLt = e3 ? a0 : a4;        // (e3,e2=T) candidates
    const float aLf = e3 ? a2 : a6;        // (e3,e2=F) candidates
    const float aL = e2 ? aLt : aLf;       // left child of chosen quarter
    const bool e1 = (aL == m16);           // true -> first pair of quarter
    const float q0 = e1 ? v0 : v2,  q1 = e1 ? v4 : v6;
    const float q2 = e1 ? v8 : v10, q3 = e1 ? v12 : v14;
    const float q4 = e2 ? q0 : q1,  q5 = e2 ? q2 : q3;
    const float vL = e3 ? q4 : q5;         // left child of chosen pair
    const bool e0 = (vL == m16);
    const int kk = (e3 ? 0 : 8) | (e2 ? 0 : 4) | (e1 ? 0 : 2) | (e0 ? 0 : 1);
    const u32 myc = ~((u32)t + ((u32)kk << 8));  // ~idx: max -> smallest idx

    // ---- wave value max: 4 row_shr prefix steps + readlane + SALU tree ----
    float pm = m16;
    WAVE_MAX_F32_STEP(pm, 0x111);  // row_shr:1
    WAVE_MAX_F32_STEP(pm, 0x112);  // row_shr:2
    WAVE_MAX_F32_STEP(pm, 0x114);  // row_shr:4
    WAVE_MAX_F32_STEP(pm, 0x118);  // row_shr:8  -> row maxes at 15/31/47/63
    const int pmb = __float_as_int(pm);
    const u32 r0 = (u32)__builtin_amdgcn_readlane(pmb, 15);
    const u32 r1 = (u32)__builtin_amdgcn_readlane(pmb, 31);
    const u32 r2 = (u32)__builtin_amdgcn_readlane(pmb, 47);
    const u32 r3 = (u32)__builtin_amdgcn_readlane(pmb, 63);
    const u32 wv = umax_(umax_(r0, r1), umax_(r2, r3));  // uniform -> SALU

    // ---- wave index reduce: matching lanes contribute ~idx, u32 max ----
    u32 cand = (__float_as_uint(m16) == wv) ? myc : 0u;
    WAVE_MAX_U32_STEP(cand, 0x111);  // row_shr:1
    WAVE_MAX_U32_STEP(cand, 0x112);  // row_shr:2
    WAVE_MAX_U32_STEP(cand, 0x114);  // row_shr:4
    WAVE_MAX_U32_STEP(cand, 0x118);  // row_shr:8
    WAVE_MAX_U32_STEP(cand, 0x142);  // row_bcast:15
    WAVE_MAX_U32_STEP(cand, 0x143);  // row_bcast:31

    const int buf = it & 1;  // double-buffered slots: 1 barrier/iter
    if ((t & 63) == 63)
      red[buf][t >> 6] =
          __longlong_as_double((long long)(((u64)wv << 32) | (u64)cand));
    __syncthreads();

    const double c = fmax(fmax(red[buf][0], red[buf][1]),
                          fmax(red[buf][2], red[buf][3]));
    const u32 widx = ~key_lo(c);  // low word = ~idx

    w = sp[widx];  // broadcast read (same address all lanes)
    lx = w.x; ly = w.y; lz = w.z;

    // off-critical-path register history update (4x cmp+cndmask, no VMEM)
    h0 = (it == t)   ? (int)widx : h0;
    h1 = (it == it1) ? (int)widx : h1;
    h2 = (it == it2) ? (int)widx : h2;
    h3 = (it == it3) ? (int)widx : h3;
  }

  // Epilogue: 4 coalesced stores per thread write all M winner indices.
  const int base = b * MPTS;
  const int goff = b * NPTS;
  gidx[base + t]       = goff + h0;
  gidx[base + 256 + t] = goff + h1;
  gidx[base + 512 + t] = goff + h2;
  gidx[base + 768 + t] = goff + h3;
}

// -------------------- Kernel 2: k=1 nearest neighbor -----------------------
// B*32 blocks x 256 threads; 128 hr points per block, 2 threads per point
// splitting the M=1024 lr points in half; packed fp32 over lr pairs.
// Argmin key: (dist_bits<<32)|j -> min = smallest dist, tie -> smallest j
// (matches np.argmin); 64-bit mins via single v_min_f64. Pair combine via
// one shfl_xor(1).
__global__ __launch_bounds__(256) void nn_kernel(const float* __restrict__ pos,
                                                 const int* __restrict__ gidx,
                                                 int* __restrict__ nng) {
#pragma clang fp contract(off)
  const int b = blockIdx.x >> 5;
  const int chunk = blockIdx.x & 31;
  const int t = threadIdx.x;

  __shared__ float lrx[MPTS], lry[MPTS], lrz[MPTS];
  for (int j = t; j < MPTS; j += 256) {
    const int g = gidx[b * MPTS + j];
    lrx[j] = pos[3 * g + 0];
    lry[j] = pos[3 * g + 1];
    lrz[j] = pos[3 * g + 2];
  }
  __syncthreads();

  const int pt = chunk * 128 + (t >> 1);
  const int half = t & 1;
  const int i = b * NPTS + pt;  // global hr point index
  const float x = pos[3 * i + 0];
  const float y = pos[3 * i + 1];
  const float z = pos[3 * i + 2];
  const v2f vx = {x, x}, vy = {y, y}, vz = {z, z};

  double best = __longlong_as_double(0x7FEFFFFFFFFFFFFFll);  // +DBL_MAX > all keys
  const int j0 = half * 512;
#pragma unroll 4
  for (int s = 0; s < 256; ++s) {
    const int j = j0 + 2 * s;
    const v2f qx = *(const v2f*)&lrx[j];
    const v2f qy = *(const v2f*)&lry[j];
    const v2f qz = *(const v2f*)&lrz[j];
    const v2f dx = vx - qx;
    const v2f dy = vy - qy;
    const v2f dz = vz - qz;
    const v2f d = (dx * dx + dy * dy) + dz * dz;
    const double p0 = mk_key(d[0], (u32)j);
    const double p1 = mk_key(d[1], (u32)(j + 1));
    best = fmin(best, fmin(p0, p1));
  }
  // pair combine across the two halves (lanes differ only in bit 0)
  const u64 bu = (u64)__double_as_longlong(best);
  const u64 ou = ((u64)(u32)__shfl_xor((int)(bu >> 32), 1, 64) << 32) |
                 (u64)(u32)__shfl_xor((int)(u32)bu, 1, 64);
  best = fmin(best, __longlong_as_double((long long)ou));
  if (half == 0) nng[i] = gidx[b * MPTS + (int)key_lo(best)];
}

// -------------------- Kernel 3: output assembly ----------------------------
// One wave per output row. Row = [x(64) | pos(3) | x[g](64) | pos[g](3)].
// Also writes output 1 (zeros, [B*N,3]) and output 2 (batch ids as floats).
__global__ __launch_bounds__(256) void assemble_kernel(const float* __restrict__ x,
                                                       const float* __restrict__ pos,
                                                       const int* __restrict__ batch,
                                                       const int* __restrict__ nng,
                                                       float* __restrict__ out) {
  const int w = (int)((blockIdx.x * 256 + threadIdx.x) >> 6);  // row
  const int lane = threadIdx.x & 63;
  if (w >= BATCH * NPTS) return;
  const int g = nng[w];

  float* o = out + (size_t)w * 134;
  o[lane] = x[(size_t)w * DIM + lane];
  o[67 + lane] = x[(size_t)g * DIM + lane];
  if (lane < 3) {
    o[64 + lane] = pos[3 * w + lane];
    o[131 + lane] = pos[3 * g + lane];
  }

  float* o2 = out + (size_t)BATCH * NPTS * 134;  // zeros output [B*N,3]
  if (lane < 3) o2[3 * w + lane] = 0.0f;
  float* o3 = o2 + (size_t)BATCH * NPTS * 3;     // batch output [B*N]
  if (lane == 0) o3[w] = (float)batch[w];
}

// ---------------------------------------------------------------------------
extern "C" void kernel_launch(void* const* d_in, const int* in_sizes, int n_in,
                              void* d_out, int out_size, void* d_ws, size_t ws_size,
                              hipStream_t stream) {
  const float* x = (const float*)d_in[0];
  const float* pos = (const float*)d_in[1];
  const int* batch = (const int*)d_in[2];

  int* gidx = (int*)d_ws;            // [B*M] global indices of sampled points
  int* nng = gidx + BATCH * MPTS;    // [B*N] global index of nearest lr point

  float* out = (float*)d_out;

  fps_kernel<<<BATCH, 256, 0, stream>>>(pos, gidx);
  nn_kernel<<<BATCH * 32, 256, 0, stream>>>(pos, gidx, nng);
  assemble_kernel<<<(BATCH * NPTS * 64) / 256, 256, 0, stream>>>(x, pos, batch, nng, out);
}